// Round 2
// baseline (107.923 us; speedup 1.0000x reference)
//
#include <hip/hip_runtime.h>
#include <hip/hip_bf16.h>
#include <math.h>

// VectorQuantizer: z [65536 x 64] fp32, codebook [1024 x 64] fp32.
// dist = (||z||^2 - 2 z.e) + ||e||^2, argmin_k, first-occurrence ties.
// Numerics identical to R4-R9 (absmax 0): exact np pairwise sumsq for S/cn;
// d via f16 split-2 3-pass MFMA; dist = (S - 2d) + cn explicit __f*_rn;
// (val, lowest-k) reduce. MFMA accumulation order preserved bit-exactly.
//
// R9 post-mortem: manual 2-slot pipeline = no change (compiler already
// scheduled it). Counters: Mfma 23 + VALU 30, ~47% no-issue, Occ 17% --
// TLP-starved at 2 waves/SIMD, and DS traffic scales with waves (every
// wave read the full 16KB B-tile). R10: split the ct (code) dimension
// across waves: 512-thr blocks, 8 waves = (rg 0..1) x (ct 0..3); each
// wave = 32 rows x its 16-code slice -> per-tile B reads drop 16KB->4KB
// per wave; grid 1024 blocks, VGPR<=128 -> 4 waves/SIMD (2x TLP), DS/CU
// halves to ~1MB (~5us). Argmin: in-wave l16 reduce -> LDS [ct][row]
// -> 4-way (val, lowest-k) merge; exact first-occurrence preserved.

#define D      64
#define K      1024
#define BLOCK  512
#define ROWS   64

typedef _Float16 half8_t __attribute__((ext_vector_type(8)));
typedef float    floatx4 __attribute__((ext_vector_type(4)));

// ws layout
#define WS_CN_OFF    0            // float[1024]         (4 KB)
#define WS_EF_OFF    4096         // _Float16[131072]    (256 KB)
// per 64-code tile t (16 KB): frag (spl,ch,ct) at half-offset
//   t*8192 + 512*((spl*2+ch)*4+ct) + 8*lane

__device__ __forceinline__ void gld_lds16(const void* g, void* l) {
    __builtin_amdgcn_global_load_lds(
        (const __attribute__((address_space(1))) void*)g,
        (__attribute__((address_space(3))) void*)l, 16, 0, 0);
}

// numpy pairwise sumsq (n=64): 8 stride-8 accs of fl(x^2), tree combine.
__device__ __forceinline__ float np_sumsq64_p(const float* __restrict__ x) {
    float r[8];
    {
        float4 v0 = *(const float4*)(x);
        float4 v1 = *(const float4*)(x + 4);
        r[0] = __fmul_rn(v0.x, v0.x); r[1] = __fmul_rn(v0.y, v0.y);
        r[2] = __fmul_rn(v0.z, v0.z); r[3] = __fmul_rn(v0.w, v0.w);
        r[4] = __fmul_rn(v1.x, v1.x); r[5] = __fmul_rn(v1.y, v1.y);
        r[6] = __fmul_rn(v1.z, v1.z); r[7] = __fmul_rn(v1.w, v1.w);
    }
#pragma unroll
    for (int i = 8; i < 64; i += 8) {
        float4 v0 = *(const float4*)(x + i);
        float4 v1 = *(const float4*)(x + i + 4);
        r[0] = __fadd_rn(r[0], __fmul_rn(v0.x, v0.x));
        r[1] = __fadd_rn(r[1], __fmul_rn(v0.y, v0.y));
        r[2] = __fadd_rn(r[2], __fmul_rn(v0.z, v0.z));
        r[3] = __fadd_rn(r[3], __fmul_rn(v0.w, v0.w));
        r[4] = __fadd_rn(r[4], __fmul_rn(v1.x, v1.x));
        r[5] = __fadd_rn(r[5], __fmul_rn(v1.y, v1.y));
        r[6] = __fadd_rn(r[6], __fmul_rn(v1.z, v1.z));
        r[7] = __fadd_rn(r[7], __fmul_rn(v1.w, v1.w));
    }
    return __fadd_rn(__fadd_rn(__fadd_rn(r[0], r[1]), __fadd_rn(r[2], r[3])),
                     __fadd_rn(__fadd_rn(r[4], r[5]), __fadd_rn(r[6], r[7])));
}

// ---- precompute: code norms + f16 split-2 B-frags in MFMA lane order ----
__global__ void vq_pre(const float* __restrict__ cb, float* __restrict__ cn,
                       _Float16* __restrict__ ef) {
    const int k = blockIdx.x * 64 + threadIdx.x;
    if (k >= K) return;
    cn[k] = np_sumsq64_p(cb + (long)k * D);
    const int t = k >> 6, ct = (k >> 4) & 3, l16 = k & 15;
#pragma unroll
    for (int ch = 0; ch < 2; ++ch)
#pragma unroll
        for (int quad = 0; quad < 4; ++quad) {
            const float* p = cb + (long)k * D + ch * 32 + quad * 8;
            half8_t h1, h2;
#pragma unroll
            for (int j = 0; j < 8; ++j) {
                float x10 = __fmul_rn(p[j], 1024.0f);        // exact pow2 scale
                _Float16 g1 = (_Float16)x10;
                h1[j] = g1;
                h2[j] = (_Float16)(__fmul_rn(__fsub_rn(x10, (float)g1), 2048.0f));
            }
            const int base = t * 8192 + 128 * quad + 8 * l16;
            *(half8_t*)(ef + base + 512 * (ch * 4 + ct))       = h1;
            *(half8_t*)(ef + base + 512 * ((2 + ch) * 4 + ct)) = h2;
        }
}

// ---- main: 64 rows x ALL 1024 codes per 8-wave block ----
// wave (rg,ct): rows rg*32..+31, code slice ct (16 codes per tile).
__global__ __launch_bounds__(BLOCK, 4) void vq_main(
    const float* __restrict__ z, const float* __restrict__ cb,
    const _Float16* __restrict__ ef, const float* __restrict__ cn,
    float* __restrict__ zq, float* __restrict__ idx_out) {
    // zf (64 x 68 f32 = 17408 B) unioned with two 16 KB frag buffers
    __shared__ __align__(16) char smem[32768];
    __shared__ float sS[ROWS];
    __shared__ float sCn[K];
    __shared__ int   sBi[ROWS];
    __shared__ float sRv[4][ROWS];
    __shared__ int   sRi[4][ROWS];
    float*    zf   = (float*)smem;
    _Float16* bufs = (_Float16*)smem;     // buf b at bufs + b*8192 (halfs)

    const int tid  = threadIdx.x;         // 0..511
    const int lane = tid & 63;
    const int wv   = tid >> 6;            // 0..7
    const int ct   = wv & 3;              // code-column slice
    const int rg   = wv >> 2;             // row group (0: rows 0-31, 1: 32-63)
    const int quad = lane >> 4;
    const int l16  = lane & 15;
    const long rowbase = (long)blockIdx.x * ROWS;

    // ---- stage z (coalesced) + all code norms ----
    const float4* gz = (const float4*)(z + rowbase * D);
#pragma unroll
    for (int i = 0; i < 2; ++i) {
        int idx4 = i * BLOCK + tid;       // 0..1023
        int r = idx4 >> 4, j = idx4 & 15;
        *(float4*)(zf + r * 68 + j * 4) = gz[idx4];
    }
#pragma unroll
    for (int i = 0; i < 2; ++i) sCn[i * BLOCK + tid] = cn[i * BLOCK + tid];
    __syncthreads();

    // row norms (exact np chain)
    if (tid < ROWS) sS[tid] = np_sumsq64_p(zf + tid * 68);

    // A-frags: register-resident f16 splits; wave -> rows rg*32 + rt*16 + l16
    half8_t a1[2][2], a2[2][2];
#pragma unroll
    for (int rt = 0; rt < 2; ++rt) {
        const int row = rg * 32 + rt * 16 + l16;
#pragma unroll
        for (int ch = 0; ch < 2; ++ch) {
            const float* p = zf + row * 68 + ch * 32 + quad * 8;
            float4 f0 = *(const float4*)(p);
            float4 f1 = *(const float4*)(p + 4);
            float xs[8] = {f0.x, f0.y, f0.z, f0.w, f1.x, f1.y, f1.z, f1.w};
#pragma unroll
            for (int j = 0; j < 8; ++j) {
                _Float16 h1 = (_Float16)xs[j];
                a1[rt][ch][j] = h1;
                a2[rt][ch][j] =
                    (_Float16)(__fmul_rn(__fsub_rn(xs[j], (float)h1), 2048.0f));
            }
        }
    }
    __syncthreads();   // all zf reads done (sS + frags); sS visible

    float myS[2][4];
#pragma unroll
    for (int rt = 0; rt < 2; ++rt)
#pragma unroll
        for (int r = 0; r < 4; ++r)
            myS[rt][r] = sS[rg * 32 + rt * 16 + quad * 4 + r];

    float bv[2][4];
    int   bi[2][4];
#pragma unroll
    for (int rt = 0; rt < 2; ++rt)
#pragma unroll
        for (int r = 0; r < 4; ++r) { bv[rt][r] = INFINITY; bi[rt][r] = 0; }

    const char* eb = (const char*)ef;

    // stage tile 0 (async DMA: wave wv copies its 2 KB eighth)
    {
        const char* g = eb + wv * 2048 + lane * 16;
        char* l = (char*)bufs + wv * 2048;       // wave-uniform dest base
#pragma unroll
        for (int i = 0; i < 2; ++i) gld_lds16(g + i * 1024, l + i * 1024);
    }
    __syncthreads();   // tile 0 staged (barrier drains vmcnt)

#pragma unroll 2
    for (int t = 0; t < 16; ++t) {
        // prefetch tile t+1 into the other buffer (async, lands by barrier)
        if (t < 15) {
            const char* g = eb + (t + 1) * 16384 + wv * 2048 + lane * 16;
            char* l = (char*)bufs + ((t + 1) & 1) * 16384 + wv * 2048;
#pragma unroll
            for (int i = 0; i < 2; ++i) gld_lds16(g + i * 1024, l + i * 1024);
        }

        // B-frags for this wave's ct only: 4 x ds_read_b128 (4 KB/wave/tile)
        const _Float16* tb = bufs + (t & 1) * 8192 + 8 * lane;
        half8_t b1[2], b2[2];
        b1[0] = *(const half8_t*)(tb + 512 * (0 * 4 + ct));
        b1[1] = *(const half8_t*)(tb + 512 * (1 * 4 + ct));
        b2[0] = *(const half8_t*)(tb + 512 * (2 * 4 + ct));
        b2[1] = *(const half8_t*)(tb + 512 * (3 * 4 + ct));
        const int kg  = t * 64 + ct * 16 + l16;
        const float cnv = sCn[kg];

        // 12 MFMAs, rt0/rt1 chains interleaved; per-element accumulation
        // order identical to R8: aM = a1b1(ch0)+a1b1(ch1);
        // aC = a1b2(ch0)+a1b2(ch1)+a2b1(ch0)+a2b1(ch1).
        const floatx4 Z4 = {0.f, 0.f, 0.f, 0.f};
        floatx4 aM0, aM1, aC0, aC1;
        aM0 = __builtin_amdgcn_mfma_f32_16x16x32_f16(a1[0][0], b1[0], Z4, 0, 0, 0);
        aM1 = __builtin_amdgcn_mfma_f32_16x16x32_f16(a1[1][0], b1[0], Z4, 0, 0, 0);
        aM0 = __builtin_amdgcn_mfma_f32_16x16x32_f16(a1[0][1], b1[1], aM0, 0, 0, 0);
        aM1 = __builtin_amdgcn_mfma_f32_16x16x32_f16(a1[1][1], b1[1], aM1, 0, 0, 0);
        aC0 = __builtin_amdgcn_mfma_f32_16x16x32_f16(a1[0][0], b2[0], Z4, 0, 0, 0);
        aC1 = __builtin_amdgcn_mfma_f32_16x16x32_f16(a1[1][0], b2[0], Z4, 0, 0, 0);
        aC0 = __builtin_amdgcn_mfma_f32_16x16x32_f16(a1[0][1], b2[1], aC0, 0, 0, 0);
        aC1 = __builtin_amdgcn_mfma_f32_16x16x32_f16(a1[1][1], b2[1], aC1, 0, 0, 0);
        aC0 = __builtin_amdgcn_mfma_f32_16x16x32_f16(a2[0][0], b1[0], aC0, 0, 0, 0);
        aC1 = __builtin_amdgcn_mfma_f32_16x16x32_f16(a2[1][0], b1[0], aC1, 0, 0, 0);
        aC0 = __builtin_amdgcn_mfma_f32_16x16x32_f16(a2[0][1], b1[1], aC0, 0, 0, 0);
        aC1 = __builtin_amdgcn_mfma_f32_16x16x32_f16(a2[1][1], b1[1], aC1, 0, 0, 0);

        // exact dist chain, unchanged: ds=fma(aC,2^-11,aM); t2=ds*2^-9;
        // dist=(S-t2)+cn; strict < keeps first occurrence.
        // C layout: col=l16 (code), row=quad*4+r
#pragma unroll
        for (int r = 0; r < 4; ++r) {
            float ds0 = fmaf(aC0[r], 0x1p-11f, aM0[r]);
            float t20 = __fmul_rn(ds0, 0x1p-9f);
            float d0  = __fadd_rn(__fsub_rn(myS[0][r], t20), cnv);
            if (d0 < bv[0][r]) { bv[0][r] = d0; bi[0][r] = kg; }
            float ds1 = fmaf(aC1[r], 0x1p-11f, aM1[r]);
            float t21 = __fmul_rn(ds1, 0x1p-9f);
            float d1  = __fadd_rn(__fsub_rn(myS[1][r], t21), cnv);
            if (d1 < bv[1][r]) { bv[1][r] = d1; bi[1][r] = kg; }
        }
        __syncthreads();  // t+1 staged; cur reads done before t+2 overwrites
    }

    // in-wave reduce over the 16 code-columns; (val, lowest index)
#pragma unroll
    for (int rt = 0; rt < 2; ++rt)
#pragma unroll
        for (int r = 0; r < 4; ++r) {
            float v = bv[rt][r];
            int   x = bi[rt][r];
#pragma unroll
            for (int off = 1; off <= 8; off <<= 1) {
                float ov = __shfl_xor(v, off);
                int   ox = __shfl_xor(x, off);
                if (ov < v || (ov == v && ox < x)) { v = ov; x = ox; }
            }
            if (l16 == 0) {
                const int row = rg * 32 + rt * 16 + quad * 4 + r;
                sRv[ct][row] = v;
                sRi[ct][row] = x;
            }
        }
    __syncthreads();

    // cross-wave (ct) combine: min value, lowest k on exact tie
    if (tid < ROWS) {
        float v = sRv[0][tid];
        int   x = sRi[0][tid];
#pragma unroll
        for (int c = 1; c < 4; ++c) {
            float ov = sRv[c][tid];
            int   ox = sRi[c][tid];
            if (ov < v || (ov == v && ox < x)) { v = ov; x = ox; }
        }
        sBi[tid] = x;
        idx_out[rowbase + tid] = (float)x;
    }
    __syncthreads();

    // ---- zq gather: zq[row] = cb[bi[row]] (cb L2-hot, coalesced writes) ----
    const float4* cb4 = (const float4*)cb;
    float4* zq4 = (float4*)(zq + rowbase * D);
#pragma unroll
    for (int i = 0; i < 2; ++i) {
        int idx4 = i * BLOCK + tid;
        int r = idx4 >> 4, j = idx4 & 15;
        zq4[idx4] = cb4[(long)sBi[r] * 16 + j];
    }
}

extern "C" void kernel_launch(void* const* d_in, const int* in_sizes, int n_in,
                              void* d_out, int out_size, void* d_ws, size_t ws_size,
                              hipStream_t stream) {
    const float* z  = (const float*)d_in[0];
    const float* cb = (const float*)d_in[1];

    const int n_rows = in_sizes[0] / D;                 // 65536
    float* zq      = (float*)d_out;
    float* idx_out = zq + (long)n_rows * D;

    float*    ws_cn = (float*)((char*)d_ws + WS_CN_OFF);
    _Float16* ws_ef = (_Float16*)((char*)d_ws + WS_EF_OFF);

    vq_pre<<<K / 64, 64, 0, stream>>>(cb, ws_cn, ws_ef);
    vq_main<<<n_rows / ROWS, BLOCK, 0, stream>>>(z, cb, ws_ef, ws_cn, zq, idx_out);
}

// Round 3
// 101.982 us; speedup vs baseline: 1.0582x; 1.0582x over previous
//
#include <hip/hip_runtime.h>
#include <hip/hip_bf16.h>
#include <math.h>

// VectorQuantizer: z [65536 x 64] fp32, codebook [1024 x 64] fp32.
// dist = (||z||^2 - 2 z.e) + ||e||^2, argmin_k, first-occurrence ties.
// Numerics identical to R4-R10 (absmax 0): exact np pairwise sumsq for S/cn;
// d via f16 split-2 3-pass MFMA; dist = (S - 2d) + cn explicit __f*_rn;
// (val, lowest-k) reduce. MFMA accumulation order preserved bit-exactly.
//
// R10 post-mortem: ct-split regressed (49us): global DS traffic was
// UNCHANGED (rows/block halved), A-frag setup 4x-redundant (bank conflicts
// 262k), and TLP was never the constraint. Real diagnosis: PHASE-LOCK --
// the per-tile barrier (needed by LDS double-buffering) forces all waves
// through ds_read/MFMA/EPI/barrier-drain in lockstep, so pipes sum
// (10+20+15us) instead of overlapping. R11: ef (256KB) is L2-resident by
// construction (read by all CUs; ~2.6TB/s/XCD demand vs 4.3 ceiling), so
// B-frags are loaded straight from global into registers: no LDS-B, no
// double-buffer, NO main-loop barriers. ef relaid out group-contiguous
// (4KB per 16-code group) for pure streaming; 2-slot (A/B) group pipeline,
// compiler emits counted vmcnt. Waves free-run and de-phase -> MFMA/VALU/
// VMEM overlap. R8 block shape restored (256thr/128rows, grid 512).

#define D      64
#define K      1024
#define BLOCK  256

typedef _Float16 half8_t __attribute__((ext_vector_type(8)));
typedef float    floatx4 __attribute__((ext_vector_type(4)));

// ws layout
#define WS_CN_OFF    0            // float[1024]         (4 KB)
#define WS_EF_OFF    4096         // _Float16[131072]    (256 KB)
// group-contiguous layout: group g = t*4+ct (16 codes) occupies bytes
// [g*4096, (g+1)*4096): slot s=(spl*2+ch) at g*4096 + s*1024 + 16*lane,
// lane = quad*16 + l16 (MFMA B lane order).

// numpy pairwise sumsq (n=64): 8 stride-8 accs of fl(x^2), tree combine.
__device__ __forceinline__ float np_sumsq64_p(const float* __restrict__ x) {
    float r[8];
    {
        float4 v0 = *(const float4*)(x);
        float4 v1 = *(const float4*)(x + 4);
        r[0] = __fmul_rn(v0.x, v0.x); r[1] = __fmul_rn(v0.y, v0.y);
        r[2] = __fmul_rn(v0.z, v0.z); r[3] = __fmul_rn(v0.w, v0.w);
        r[4] = __fmul_rn(v1.x, v1.x); r[5] = __fmul_rn(v1.y, v1.y);
        r[6] = __fmul_rn(v1.z, v1.z); r[7] = __fmul_rn(v1.w, v1.w);
    }
#pragma unroll
    for (int i = 8; i < 64; i += 8) {
        float4 v0 = *(const float4*)(x + i);
        float4 v1 = *(const float4*)(x + i + 4);
        r[0] = __fadd_rn(r[0], __fmul_rn(v0.x, v0.x));
        r[1] = __fadd_rn(r[1], __fmul_rn(v0.y, v0.y));
        r[2] = __fadd_rn(r[2], __fmul_rn(v0.z, v0.z));
        r[3] = __fadd_rn(r[3], __fmul_rn(v0.w, v0.w));
        r[4] = __fadd_rn(r[4], __fmul_rn(v1.x, v1.x));
        r[5] = __fadd_rn(r[5], __fmul_rn(v1.y, v1.y));
        r[6] = __fadd_rn(r[6], __fmul_rn(v1.z, v1.z));
        r[7] = __fadd_rn(r[7], __fmul_rn(v1.w, v1.w));
    }
    return __fadd_rn(__fadd_rn(__fadd_rn(r[0], r[1]), __fadd_rn(r[2], r[3])),
                     __fadd_rn(__fadd_rn(r[4], r[5]), __fadd_rn(r[6], r[7])));
}

// ---- precompute: code norms + f16 split-2 B-frags, group-contiguous ----
__global__ void vq_pre(const float* __restrict__ cb, float* __restrict__ cn,
                       _Float16* __restrict__ ef) {
    const int k = blockIdx.x * 64 + threadIdx.x;
    if (k >= K) return;
    cn[k] = np_sumsq64_p(cb + (long)k * D);
    const int t = k >> 6, ct = (k >> 4) & 3, l16 = k & 15;
#pragma unroll
    for (int ch = 0; ch < 2; ++ch)
#pragma unroll
        for (int quad = 0; quad < 4; ++quad) {
            const float* p = cb + (long)k * D + ch * 32 + quad * 8;
            half8_t h1, h2;
#pragma unroll
            for (int j = 0; j < 8; ++j) {
                float x10 = __fmul_rn(p[j], 1024.0f);        // exact pow2 scale
                _Float16 g1 = (_Float16)x10;
                h1[j] = g1;
                h2[j] = (_Float16)(__fmul_rn(__fsub_rn(x10, (float)g1), 2048.0f));
            }
            // half-offset within group: slot*512 + 128*quad + 8*l16
            const int base = t * 8192 + ct * 2048 + 128 * quad + 8 * l16;
            *(half8_t*)(ef + base + 512 * (ch))       = h1;   // spl0: slots 0,1
            *(half8_t*)(ef + base + 512 * (2 + ch))   = h2;   // spl1: slots 2,3
        }
}

// ---- main: 128 rows x ALL 1024 codes per 4-wave block; barrier-free loop ----
__global__ __launch_bounds__(BLOCK, 2) void vq_main(
    const float* __restrict__ z, const float* __restrict__ cb,
    const _Float16* __restrict__ ef, const float* __restrict__ cn,
    float* __restrict__ zq, float* __restrict__ idx_out) {
    __shared__ __align__(16) float zf[128 * 68];   // 34816 B, +68 stride
    __shared__ float sS[128];
    __shared__ float sCn[K];
    __shared__ int   sBi[128];

    const int tid  = threadIdx.x;
    const int lane = tid & 63;
    const int wv   = tid >> 6;
    const int quad = lane >> 4;
    const int l16  = lane & 15;
    const long rowbase = (long)blockIdx.x * 128;

    // ---- stage z (coalesced) + all code norms ----
    const float4* gz = (const float4*)(z + rowbase * D);
#pragma unroll
    for (int i = 0; i < 8; ++i) {
        int idx4 = i * BLOCK + tid;
        int r = idx4 >> 4, j = idx4 & 15;
        *(float4*)(zf + r * 68 + j * 4) = gz[idx4];
    }
#pragma unroll
    for (int i = 0; i < 4; ++i) sCn[i * 256 + tid] = cn[i * 256 + tid];
    __syncthreads();

    // row norms (exact np chain)
    if (tid < 128) sS[tid] = np_sumsq64_p(zf + tid * 68);

    // A-frags: register-resident f16 splits; wave wv -> rows wv*32 .. +31
    half8_t a1[2][2], a2[2][2];
#pragma unroll
    for (int rt = 0; rt < 2; ++rt) {
        const int row = wv * 32 + rt * 16 + l16;
#pragma unroll
        for (int ch = 0; ch < 2; ++ch) {
            const float* p = zf + row * 68 + ch * 32 + quad * 8;
            float4 f0 = *(const float4*)(p);
            float4 f1 = *(const float4*)(p + 4);
            float xs[8] = {f0.x, f0.y, f0.z, f0.w, f1.x, f1.y, f1.z, f1.w};
#pragma unroll
            for (int j = 0; j < 8; ++j) {
                _Float16 h1 = (_Float16)xs[j];
                a1[rt][ch][j] = h1;
                a2[rt][ch][j] =
                    (_Float16)(__fmul_rn(__fsub_rn(xs[j], (float)h1), 2048.0f));
            }
        }
    }
    __syncthreads();   // sS visible to all waves

    float myS[2][4];
#pragma unroll
    for (int rt = 0; rt < 2; ++rt)
#pragma unroll
        for (int r = 0; r < 4; ++r)
            myS[rt][r] = sS[wv * 32 + rt * 16 + quad * 4 + r];

    float bv[2][4];
    int   bi[2][4];
#pragma unroll
    for (int rt = 0; rt < 2; ++rt)
#pragma unroll
        for (int r = 0; r < 4; ++r) { bv[rt][r] = INFINITY; bi[rt][r] = 0; }

    const char* eb = (const char*)ef + 16 * lane;

// 4 streaming 1KB global loads (L2-hot), one 16-code group
#define LOADG(b1_, b2_, g_) do {                                              \
        const char* p_ = eb + (size_t)(g_) * 4096;                            \
        b1_[0] = *(const half8_t*)(p_);                                       \
        b1_[1] = *(const half8_t*)(p_ + 1024);                                \
        b2_[0] = *(const half8_t*)(p_ + 2048);                                \
        b2_[1] = *(const half8_t*)(p_ + 3072);                                \
    } while (0)

// 12 MFMAs (rt0/rt1 interleaved; per-element accumulation order = R8)
// + exact EPI: ds=fma(aC,2^-11,aM); t2=ds*2^-9; dist=(S-t2)+cn; strict <.
#define COMPUTE(b1_, b2_, g_) do {                                            \
        const int   kg_  = (g_) * 16 + l16;                                   \
        const float cnv_ = sCn[kg_];                                          \
        const floatx4 Z4_ = {0.f, 0.f, 0.f, 0.f};                             \
        floatx4 aM0, aM1, aC0, aC1;                                           \
        aM0 = __builtin_amdgcn_mfma_f32_16x16x32_f16(a1[0][0], b1_[0], Z4_, 0, 0, 0); \
        aM1 = __builtin_amdgcn_mfma_f32_16x16x32_f16(a1[1][0], b1_[0], Z4_, 0, 0, 0); \
        aM0 = __builtin_amdgcn_mfma_f32_16x16x32_f16(a1[0][1], b1_[1], aM0, 0, 0, 0); \
        aM1 = __builtin_amdgcn_mfma_f32_16x16x32_f16(a1[1][1], b1_[1], aM1, 0, 0, 0); \
        aC0 = __builtin_amdgcn_mfma_f32_16x16x32_f16(a1[0][0], b2_[0], Z4_, 0, 0, 0); \
        aC1 = __builtin_amdgcn_mfma_f32_16x16x32_f16(a1[1][0], b2_[0], Z4_, 0, 0, 0); \
        aC0 = __builtin_amdgcn_mfma_f32_16x16x32_f16(a1[0][1], b2_[1], aC0, 0, 0, 0); \
        aC1 = __builtin_amdgcn_mfma_f32_16x16x32_f16(a1[1][1], b2_[1], aC1, 0, 0, 0); \
        aC0 = __builtin_amdgcn_mfma_f32_16x16x32_f16(a2[0][0], b1_[0], aC0, 0, 0, 0); \
        aC1 = __builtin_amdgcn_mfma_f32_16x16x32_f16(a2[1][0], b1_[0], aC1, 0, 0, 0); \
        aC0 = __builtin_amdgcn_mfma_f32_16x16x32_f16(a2[0][1], b1_[1], aC0, 0, 0, 0); \
        aC1 = __builtin_amdgcn_mfma_f32_16x16x32_f16(a2[1][1], b1_[1], aC1, 0, 0, 0); \
        _Pragma("unroll")                                                     \
        for (int r = 0; r < 4; ++r) {                                         \
            float ds0 = fmaf(aC0[r], 0x1p-11f, aM0[r]);                       \
            float d0  = __fadd_rn(__fsub_rn(myS[0][r],                        \
                            __fmul_rn(ds0, 0x1p-9f)), cnv_);                  \
            if (d0 < bv[0][r]) { bv[0][r] = d0; bi[0][r] = kg_; }             \
            float ds1 = fmaf(aC1[r], 0x1p-11f, aM1[r]);                       \
            float d1  = __fadd_rn(__fsub_rn(myS[1][r],                        \
                            __fmul_rn(ds1, 0x1p-9f)), cnv_);                  \
            if (d1 < bv[1][r]) { bv[1][r] = d1; bi[1][r] = kg_; }             \
        }                                                                     \
    } while (0)

    // 2-slot pipeline over 64 groups; no barriers, waves free-run
    half8_t b1A[2], b2A[2], b1B[2], b2B[2];
    LOADG(b1A, b2A, 0);
    for (int g = 0; g < 64; g += 2) {
        LOADG(b1B, b2B, g + 1);
        COMPUTE(b1A, b2A, g);
        if (g < 62) LOADG(b1A, b2A, g + 2);
        COMPUTE(b1B, b2B, g + 1);
    }

#undef LOADG
#undef COMPUTE

    // reduce over the 16 code-columns; (val, lowest index) = first occurrence
#pragma unroll
    for (int rt = 0; rt < 2; ++rt)
#pragma unroll
        for (int r = 0; r < 4; ++r) {
            float v = bv[rt][r];
            int   x = bi[rt][r];
#pragma unroll
            for (int off = 1; off <= 8; off <<= 1) {
                float ov = __shfl_xor(v, off);
                int   ox = __shfl_xor(x, off);
                if (ov < v || (ov == v && ox < x)) { v = ov; x = ox; }
            }
            if (l16 == 0) {
                const int rl = wv * 32 + rt * 16 + quad * 4 + r;
                sBi[rl] = x;
                idx_out[rowbase + rl] = (float)x;
            }
        }
    __syncthreads();

    // ---- zq gather: zq[row] = cb[bi[row]] (cb L2-hot, coalesced writes) ----
    const float4* cb4 = (const float4*)cb;
    float4* zq4 = (float4*)(zq + rowbase * D);
#pragma unroll
    for (int i = 0; i < 8; ++i) {
        int idx4 = i * BLOCK + tid;
        int r = idx4 >> 4, j = idx4 & 15;
        zq4[idx4] = cb4[(long)sBi[r] * 16 + j];
    }
}

extern "C" void kernel_launch(void* const* d_in, const int* in_sizes, int n_in,
                              void* d_out, int out_size, void* d_ws, size_t ws_size,
                              hipStream_t stream) {
    const float* z  = (const float*)d_in[0];
    const float* cb = (const float*)d_in[1];

    const int n_rows = in_sizes[0] / D;                 // 65536
    float* zq      = (float*)d_out;
    float* idx_out = zq + (long)n_rows * D;

    float*    ws_cn = (float*)((char*)d_ws + WS_CN_OFF);
    _Float16* ws_ef = (_Float16*)((char*)d_ws + WS_EF_OFF);

    vq_pre<<<K / 64, 64, 0, stream>>>(cb, ws_cn, ws_ef);
    vq_main<<<n_rows / 128, BLOCK, 0, stream>>>(z, cb, ws_ef, ws_cn, zq, idx_out);
}